// Round 1
// baseline (101.565 us; speedup 1.0000x reference)
//
#include <hip/hip_runtime.h>

// Causal depthwise conv1d, B=8, T=8192, F=1024, K=4, fp32.
// y[b,t,f] = sum_{k=0..3} x[b, t-3+k, f] * W[k,0,f] + bias[f]   (x=0 for t<0)
//
// Layout: x is (B,T,F) with F innermost -> float4 over features is coalesced.
// Each thread: 4 consecutive features (float4) x TT consecutive timesteps,
// sliding 3-deep register window (each x row loaded once per owning thread).

constexpr int FEAT   = 1024;
constexpr int F4     = FEAT / 4;        // 256 float4 groups per row
constexpr int TSTEPS = 8192;
constexpr int TT     = 16;              // timesteps per thread
constexpr int NTILE  = TSTEPS / TT;     // 512 tiles per batch row

__global__ __launch_bounds__(256) void causal_conv1d_kernel(
    const float4* __restrict__ x4,
    const float*  __restrict__ W,     // (K=4, 1, F) flat: W[k*F + f]
    const float*  __restrict__ bias,  // (F,)
    float4*       __restrict__ y4)
{
    int idx = blockIdx.x * blockDim.x + threadIdx.x;
    // idx -> (batch, ttile, f4). f4 innermost so consecutive lanes are
    // consecutive 16B chunks of the same (b,t) row -> fully coalesced.
    int f4    = idx & (F4 - 1);
    int tmp   = idx >> 8;               // / 256
    int ttile = tmp & (NTILE - 1);      // % 512
    int batch = tmp >> 9;               // / 512

    int t0 = ttile * TT;
    int base = (batch * TSTEPS + t0) * F4 + f4;   // float4 index (max ~16.7M, fits int)

    // Per-feature weights: W[k][f4*4 .. f4*4+3]
    const float4* W4 = reinterpret_cast<const float4*>(W);
    float4 w0 = W4[0 * F4 + f4];
    float4 w1 = W4[1 * F4 + f4];
    float4 w2 = W4[2 * F4 + f4];
    float4 w3 = W4[3 * F4 + f4];
    float4 bb = reinterpret_cast<const float4*>(bias)[f4];

    // 3-deep causal history window
    float4 h0 = {0.f, 0.f, 0.f, 0.f};
    float4 h1 = h0, h2 = h0;
    if (t0 > 0) {
        h0 = x4[base - 3 * F4];
        h1 = x4[base - 2 * F4];
        h2 = x4[base - 1 * F4];
    }

#pragma unroll
    for (int i = 0; i < TT; ++i) {
        float4 cur = x4[base + i * F4];
        float4 o;
        o.x = fmaf(w3.x, cur.x, fmaf(w2.x, h2.x, fmaf(w1.x, h1.x, fmaf(w0.x, h0.x, bb.x))));
        o.y = fmaf(w3.y, cur.y, fmaf(w2.y, h2.y, fmaf(w1.y, h1.y, fmaf(w0.y, h0.y, bb.y))));
        o.z = fmaf(w3.z, cur.z, fmaf(w2.z, h2.z, fmaf(w1.z, h1.z, fmaf(w0.z, h0.z, bb.z))));
        o.w = fmaf(w3.w, cur.w, fmaf(w2.w, h2.w, fmaf(w1.w, h1.w, fmaf(w0.w, h0.w, bb.w))));
        y4[base + i * F4] = o;
        h0 = h1; h1 = h2; h2 = cur;
    }
}

extern "C" void kernel_launch(void* const* d_in, const int* in_sizes, int n_in,
                              void* d_out, int out_size, void* d_ws, size_t ws_size,
                              hipStream_t stream) {
    const float4* x4 = (const float4*)d_in[0];
    const float*  W  = (const float*)d_in[1];
    const float*  b  = (const float*)d_in[2];
    float4* y4 = (float4*)d_out;

    constexpr int B = 8;
    int total_threads = B * NTILE * F4;          // 8 * 512 * 256 = 1,048,576
    int block = 256;
    int grid  = total_threads / block;           // 4096
    causal_conv1d_kernel<<<grid, block, 0, stream>>>(x4, W, b, y4);
}

// Round 3
// 86.318 us; speedup vs baseline: 1.1766x; 1.1766x over previous
//
#include <hip/hip_runtime.h>

// Causal depthwise conv1d, B=8, T=8192, F=1024, K=4, fp32.
// y[b,t,f] = sum_{k=0..3} x[b, t-3+k, f] * W[k,0,f] + bias[f]   (x=0 for t<0)
//
// Memory-bound (8 FLOP per 8 B ideal). Each thread: 4 consecutive features
// (native 16B vector, coalesced over innermost F dim) x TT=32 consecutive
// timesteps with a 3-deep register history window. Halo = 3/32 extra reads;
// XCD swizzle puts ttile-adjacent blocks on the same XCD L2 so halos hit.
// y stores are non-temporal (never re-read) to preserve L2/L3 for x.

typedef float f32x4 __attribute__((ext_vector_type(4)));  // native vec: NT-store OK

constexpr int FEAT   = 1024;
constexpr int F4     = FEAT / 4;        // 256 vec4 groups per row
constexpr int TSTEPS = 8192;
constexpr int TT     = 32;              // timesteps per thread
constexpr int NTILE  = TSTEPS / TT;     // 256 tiles per batch row
constexpr int NXCD   = 8;

__global__ __launch_bounds__(256) void causal_conv1d_kernel(
    const f32x4* __restrict__ x4,
    const float* __restrict__ W,     // (K=4, 1, F) flat: W[k*F + f]
    const float* __restrict__ bias,  // (F,)
    f32x4*       __restrict__ y4)
{
    // XCD-aware swizzle: grid = 2048 blocks, 2048 % 8 == 0 -> bijective.
    int nblk = gridDim.x;
    int bid  = blockIdx.x;
    int lid  = (bid % NXCD) * (nblk / NXCD) + bid / NXCD;

    int idx = lid * 256 + threadIdx.x;
    int f4    = idx & (F4 - 1);
    int tmp   = idx >> 8;               // logical block id
    int ttile = tmp & (NTILE - 1);      // % 256
    int batch = tmp >> 8;               // / 256

    int t0 = ttile * TT;
    int base = (batch * TSTEPS + t0) * F4 + f4;   // vec4 index, fits int

    const f32x4* W4 = reinterpret_cast<const f32x4*>(W);
    f32x4 w0 = W4[0 * F4 + f4];
    f32x4 w1 = W4[1 * F4 + f4];
    f32x4 w2 = W4[2 * F4 + f4];
    f32x4 w3 = W4[3 * F4 + f4];
    f32x4 bb = reinterpret_cast<const f32x4*>(bias)[f4];

    // 3-deep causal history
    f32x4 h0 = {0.f, 0.f, 0.f, 0.f};
    f32x4 h1 = h0, h2 = h0;
    if (t0 > 0) {
        h0 = x4[base - 3 * F4];
        h1 = x4[base - 2 * F4];
        h2 = x4[base - 1 * F4];
    }

    // 4 x unroll-8: bounded VGPR use, 8 loads in flight per chunk.
    for (int c = 0; c < TT / 8; ++c) {
        f32x4 cur[8];
#pragma unroll
        for (int i = 0; i < 8; ++i)
            cur[i] = x4[base + (c * 8 + i) * F4];
#pragma unroll
        for (int i = 0; i < 8; ++i) {
            f32x4 p0 = (i >= 3) ? cur[i - 3] : (i == 0 ? h0 : (i == 1 ? h1 : h2));
            f32x4 p1 = (i >= 2) ? cur[i - 2] : (i == 0 ? h1 : h2);
            f32x4 p2 = (i >= 1) ? cur[i - 1] : h2;
            f32x4 p3 = cur[i];
            f32x4 o;
            o.x = fmaf(w3.x, p3.x, fmaf(w2.x, p2.x, fmaf(w1.x, p1.x, fmaf(w0.x, p0.x, bb.x))));
            o.y = fmaf(w3.y, p3.y, fmaf(w2.y, p2.y, fmaf(w1.y, p1.y, fmaf(w0.y, p0.y, bb.y))));
            o.z = fmaf(w3.z, p3.z, fmaf(w2.z, p2.z, fmaf(w1.z, p1.z, fmaf(w0.z, p0.z, bb.z))));
            o.w = fmaf(w3.w, p3.w, fmaf(w2.w, p2.w, fmaf(w1.w, p1.w, fmaf(w0.w, p0.w, bb.w))));
            __builtin_nontemporal_store(o, &y4[base + (c * 8 + i) * F4]);
        }
        h0 = cur[5]; h1 = cur[6]; h2 = cur[7];
    }
}

extern "C" void kernel_launch(void* const* d_in, const int* in_sizes, int n_in,
                              void* d_out, int out_size, void* d_ws, size_t ws_size,
                              hipStream_t stream) {
    const f32x4* x4 = (const f32x4*)d_in[0];
    const float* W  = (const float*)d_in[1];
    const float* b  = (const float*)d_in[2];
    f32x4* y4 = (f32x4*)d_out;

    constexpr int B = 8;
    int total_threads = B * NTILE * F4;          // 8 * 256 * 256 = 524,288
    int block = 256;
    int grid  = total_threads / block;           // 2048
    causal_conv1d_kernel<<<grid, block, 0, stream>>>(x4, W, b, y4);
}